// Round 1
// baseline (161.168 us; speedup 1.0000x reference)
//
#include <hip/hip_runtime.h>
#include <math.h>

#define NC 6
#define RM 16
#define TOPK 10
#define BSZ 32
#define G 20
#define A_TOT 8400
#define NBA (BSZ * A_TOT)
#define NBLK_PREP (NBA / 256)          /* 1050 */
#define NBLK_LOSS ((NBA + 255) / 256)  /* 1050 */
#define MAXCAND 1024

__device__ __forceinline__ void anchor_decode(int a, int& lvl, int& ai, int& w, int& hw, float& s) {
    if (a < 6400)      { lvl = 0; ai = a;        w = 80; hw = 6400; s = 8.f; }
    else if (a < 8000) { lvl = 1; ai = a - 6400; w = 40; hw = 1600; s = 16.f; }
    else               { lvl = 2; ai = a - 8000; w = 20; hw = 400;  s = 32.f; }
}

// task-aligned metric for one (gt, anchor) pair; returns 0 if anchor center not in gt
__device__ __forceinline__ float align_from(const float* __restrict__ trow, float logit,
                                            float4 box, float ax, float ay) {
    float cx = trow[2] * 640.f, cy = trow[3] * 640.f;
    float hwd = trow[4] * 320.f, hh = trow[5] * 320.f;
    float gx1 = cx - hwd, gy1 = cy - hh, gx2 = cx + hwd, gy2 = cy + hh;
    float mn = fminf(fminf(ax - gx1, ay - gy1), fminf(gx2 - ax, gy2 - ay));
    if (mn <= 1e-9f) return 0.f;
    const float eps = 1e-7f;
    float x1 = fmaxf(gx1, box.x), y1 = fmaxf(gy1, box.y);
    float x2 = fminf(gx2, box.z), y2 = fminf(gy2, box.w);
    float inter = fmaxf(x2 - x1, 0.f) * fmaxf(y2 - y1, 0.f);
    float gw = fmaxf(gx2 - gx1, eps), gh = fmaxf(gy2 - gy1, eps);
    float w2 = fmaxf(box.z - box.x, eps), h2 = fmaxf(box.w - box.y, eps);
    float uni = gw * gh + w2 * h2 - inter + eps;
    float iou = inter / uni;
    float sc = 1.f / (1.f + __expf(-logit));
    float i2 = iou * iou;
    return sqrtf(sc) * (i2 * i2 * i2);
}

// ------- Kernel 1: decode boxes, logZ, base BCE, zero mask -------
// Quad-split: 4 threads per quad of consecutive anchors; thread sd does side sd's
// 16-channel single-pass softmax. 4x4 side<->anchor transpose done IN-REGISTER
// via __shfl_xor (masks 1,2) instead of LDS: no LDS arrays, one less barrier,
// zero LDS bank conflicts.
__global__ __launch_bounds__(256) void k_prep(
        const float* __restrict__ p0, const float* __restrict__ p1, const float* __restrict__ p2,
        float* __restrict__ pd_boxes, float* __restrict__ logZ,
        unsigned int* __restrict__ mask, float* __restrict__ partial_prep,
        unsigned int* __restrict__ done) {
    int tid = blockIdx.x * 256 + threadIdx.x;
    int q = tid >> 2;           // quad index
    int sd = tid & 3;           // side handled by this thread
    int idx4 = q * 4;
    int b = idx4 / A_TOT, a4 = idx4 % A_TOT;
    int lvl, ai, w, hw; float s;
    anchor_decode(a4, lvl, ai, w, hw, s);
    const float* p = (lvl == 0) ? p0 : ((lvl == 1) ? p1 : p2);
    const float* base = p + (size_t)b * 70 * hw + ai;

    float4 se = make_float4(0, 0, 0, 0), sk = make_float4(0, 0, 0, 0);
    #pragma unroll
    for (int k = 0; k < RM; ++k) {
        float4 v = *(const float4*)(base + (size_t)(sd * RM + k) * hw);
        float fk = (float)k;
        float ex = __expf(v.x); se.x += ex; sk.x += ex * fk;
        float ey = __expf(v.y); se.y += ey; sk.y += ey * fk;
        float ez = __expf(v.z); se.z += ez; sk.z += ez * fk;
        float ew = __expf(v.w); se.w += ew; sk.w += ew * fk;
    }
    // row (this thread): side sd's dist / logZ for the quad's 4 anchors
    float d0 = sk.x / se.x, d1 = sk.y / se.y, d2 = sk.z / se.z, d3 = sk.w / se.w;
    float z0 = __logf(se.x), z1 = __logf(se.y), z2 = __logf(se.z), z3 = __logf(se.w);

    // in-wave 4x4 transpose within each quad (lanes 4q..4q+3): after this,
    // thread sd holds all 4 sides of anchor (quad, j=sd).
    bool lo = (sd & 1) == 0, hi = (sd & 2) == 0;
    // dist
    float ea0 = __shfl_xor(d0, 1), ea1 = __shfl_xor(d1, 1), ea2 = __shfl_xor(d2, 1), ea3 = __shfl_xor(d3, 1);
    float na0 = lo ? d0 : ea1, na1 = lo ? ea0 : d1, na2 = lo ? d2 : ea3, na3 = lo ? ea2 : d3;
    float fa0 = __shfl_xor(na0, 2), fa1 = __shfl_xor(na1, 2), fa2 = __shfl_xor(na2, 2), fa3 = __shfl_xor(na3, 2);
    float ma0 = hi ? na0 : fa2, ma1 = hi ? na1 : fa3, ma2 = hi ? fa0 : na2, ma3 = hi ? fa1 : na3;
    // logZ
    float za0 = __shfl_xor(z0, 1), za1 = __shfl_xor(z1, 1), za2 = __shfl_xor(z2, 1), za3 = __shfl_xor(z3, 1);
    float zb0 = lo ? z0 : za1, zb1 = lo ? za0 : z1, zb2 = lo ? z2 : za3, zb3 = lo ? za2 : z3;
    float zc0 = __shfl_xor(zb0, 2), zc1 = __shfl_xor(zb1, 2), zc2 = __shfl_xor(zb2, 2), zc3 = __shfl_xor(zb3, 2);
    float zd0 = hi ? zb0 : zc2, zd1 = hi ? zb1 : zc3, zd2 = hi ? zc0 : zb2, zd3 = hi ? zc1 : zb3;

    float ax = ((float)(ai % w + sd) + 0.5f) * s;
    float ay = ((float)(ai / w) + 0.5f) * s;
    ((float4*)pd_boxes)[tid] = make_float4(ax - ma0 * s, ay - ma1 * s, ax + ma2 * s, ay + ma3 * s);
    ((float4*)logZ)[tid] = make_float4(zd0, zd1, zd2, zd3);
    mask[tid] = 0u;
    if (tid == 0) *done = 0u;

    // base BCE (target=0 term) for class channels 64+sd (+68+sd for sd<2)
    float bce = 0.f;
    {
        float4 x = *(const float4*)(base + (size_t)(64 + sd) * hw);
        bce += fmaxf(x.x, 0.f) + __logf(1.f + __expf(-fabsf(x.x)));
        bce += fmaxf(x.y, 0.f) + __logf(1.f + __expf(-fabsf(x.y)));
        bce += fmaxf(x.z, 0.f) + __logf(1.f + __expf(-fabsf(x.z)));
        bce += fmaxf(x.w, 0.f) + __logf(1.f + __expf(-fabsf(x.w)));
        if (sd < 2) {
            float4 y = *(const float4*)(base + (size_t)(68 + sd) * hw);
            bce += fmaxf(y.x, 0.f) + __logf(1.f + __expf(-fabsf(y.x)));
            bce += fmaxf(y.y, 0.f) + __logf(1.f + __expf(-fabsf(y.y)));
            bce += fmaxf(y.z, 0.f) + __logf(1.f + __expf(-fabsf(y.z)));
            bce += fmaxf(y.w, 0.f) + __logf(1.f + __expf(-fabsf(y.w)));
        }
    }

    // block reduce bce
    __shared__ float part[4];
    int lane = threadIdx.x & 63, wv = threadIdx.x >> 6;
    #pragma unroll
    for (int off = 32; off > 0; off >>= 1) bce += __shfl_down(bce, off);
    if (lane == 0) part[wv] = bce;
    __syncthreads();
    if (threadIdx.x == 0)
        partial_prep[blockIdx.x] = part[0] + part[1] + part[2] + part[3];
}

// prefer higher value; on tie prefer LOWER index (matches jax.lax.top_k)
__device__ __forceinline__ bool cand_better(float av, int ai_, float bv, int bi_) {
    if (av > bv) return true;
    if (av < bv) return false;
    if (ai_ < 0) return false;
    if (bi_ < 0) return true;
    return ai_ < bi_;
}

// ------- Kernel 2: per-(b,g) bounded cell scan + top-10 -> mask bits, row max -------
// Top-10 is now: per-wave barrier-free top-10 via __shfl_xor butterflies, then a
// single wave-0 merge of the 4x10 survivors. amax comes from the scan phase.
// Barriers per block: 3 (was ~22).
__global__ __launch_bounds__(256) void k_align(
        const float* __restrict__ targets,
        const float* __restrict__ pd_boxes,
        const float* __restrict__ p0, const float* __restrict__ p1, const float* __restrict__ p2,
        float* __restrict__ amax, unsigned int* __restrict__ mask) {
    __shared__ float cval[MAXCAND];
    __shared__ int   cidx[MAXCAND];
    __shared__ int   cnt_s;
    __shared__ float wtv[4][TOPK];
    __shared__ int   wti[4][TOPK];
    __shared__ float redf[4];

    int bg = blockIdx.x;
    int b = bg / G;
    int g = bg % G;
    const float* t = targets + (size_t)bg * 6;
    int lab = (int)t[1];
    const float* cb[3];
    cb[0] = p0 + (size_t)b * 70 * 6400 + (size_t)(64 + lab) * 6400;
    cb[1] = p1 + (size_t)b * 70 * 1600 + (size_t)(64 + lab) * 1600;
    cb[2] = p2 + (size_t)b * 70 * 400  + (size_t)(64 + lab) * 400;
    const float4* pb = (const float4*)pd_boxes + (size_t)b * A_TOT;

    float cx = t[2] * 640.f, cy = t[3] * 640.f;
    float hwd = t[4] * 320.f, hh = t[5] * 320.f;
    float gx1 = cx - hwd, gy1 = cy - hh, gx2 = cx + hwd, gy2 = cy + hh;

    const float sv3[3] = {8.f, 16.f, 32.f};
    const int   wv3[3] = {80, 40, 20};
    const int   ov3[3] = {0, 6400, 8000};
    int x0[3], y0[3], nx[3], ncell[3];
    int ntot = 0;
    #pragma unroll
    for (int l = 0; l < 3; ++l) {
        float s = sv3[l]; int w = wv3[l];
        int xa = max(0, (int)floorf(gx1 / s - 0.5f));
        int xb = min(w - 1, (int)ceilf(gx2 / s - 0.5f));
        int ya = max(0, (int)floorf(gy1 / s - 0.5f));
        int yb = min(w - 1, (int)ceilf(gy2 / s - 0.5f));
        x0[l] = xa; y0[l] = ya;
        nx[l] = max(0, xb - xa + 1);
        int nyl = max(0, yb - ya + 1);
        ncell[l] = nx[l] * nyl;
        ntot += ncell[l];
    }

    if (threadIdx.x == 0) cnt_s = 0;
    __syncthreads();

    float lmax = -1.f;
    for (int i = threadIdx.x; i < ntot; i += 256) {
        int l = 0, loc = i;
        if (loc >= ncell[0]) { loc -= ncell[0]; l = 1; }
        if (l == 1 && loc >= ncell[1]) { loc -= ncell[1]; l = 2; }
        int iy = loc / nx[l], ix = loc % nx[l];
        ix += x0[l]; iy += y0[l];
        float s = sv3[l]; int w = wv3[l];
        float ax = ((float)ix + 0.5f) * s, ay = ((float)iy + 0.5f) * s;
        int a = ov3[l] + iy * w + ix;
        float logit = cb[l][iy * w + ix];
        float al = align_from(t, logit, pb[a], ax, ay);
        if (al > 0.f) {
            lmax = fmaxf(lmax, al);
            int p = atomicAdd(&cnt_s, 1);
            if (p < MAXCAND) { cval[p] = al; cidx[p] = a; }
        }
    }
    int lane = threadIdx.x & 63, wv = threadIdx.x >> 6;
    #pragma unroll
    for (int off = 32; off > 0; off >>= 1) lmax = fmaxf(lmax, __shfl_xor(lmax, off));
    if (lane == 0) redf[wv] = lmax;
    __syncthreads();   // covers redf AND cval/cidx visibility
    if (threadIdx.x == 0)
        amax[bg] = fmaxf(fmaxf(fmaxf(redf[0], redf[1]), fmaxf(redf[2], redf[3])), 0.f);

    int cnt = min(cnt_s, MAXCAND);
    float mv[MAXCAND / 256];
    int   mi[MAXCAND / 256];
    #pragma unroll
    for (int r = 0; r < MAXCAND / 256; ++r) {
        int p = threadIdx.x + r * 256;
        mv[r] = (p < cnt) ? cval[p] : -1.f;
        mi[r] = (p < cnt) ? cidx[p] : -1;
    }

    // per-wave top-10: no barriers, butterfly gives every lane the winner
    for (int it = 0; it < TOPK; ++it) {
        float v = -1.f; int vi = -1;
        #pragma unroll
        for (int r = 0; r < MAXCAND / 256; ++r)
            if (cand_better(mv[r], mi[r], v, vi)) { v = mv[r]; vi = mi[r]; }
        #pragma unroll
        for (int off = 1; off < 64; off <<= 1) {
            float ov = __shfl_xor(v, off);
            int   oi = __shfl_xor(vi, off);
            if (cand_better(ov, oi, v, vi)) { v = ov; vi = oi; }
        }
        if (vi < 0) {
            if (lane == 0)
                for (int j = it; j < TOPK; ++j) { wtv[wv][j] = -1.f; wti[wv][j] = -1; }
            break;
        }
        if (lane == 0) { wtv[wv][it] = v; wti[wv][it] = vi; }
        #pragma unroll
        for (int r = 0; r < MAXCAND / 256; ++r)
            if (mi[r] == vi) { mv[r] = -1.f; mi[r] = -1; }
    }
    __syncthreads();

    // wave 0 merges the 40 survivors (global top-10 is a subset of per-part top-10s)
    if (wv == 0) {
        float v4 = -1.f; int i4 = -1;
        if (lane < 4 * TOPK) { v4 = wtv[lane / TOPK][lane % TOPK]; i4 = wti[lane / TOPK][lane % TOPK]; }
        unsigned int* mrow = mask + (size_t)b * A_TOT;
        for (int it = 0; it < TOPK; ++it) {
            float v = v4; int vi = i4;
            #pragma unroll
            for (int off = 1; off < 64; off <<= 1) {
                float ov = __shfl_xor(v, off);
                int   oi = __shfl_xor(vi, off);
                if (cand_better(ov, oi, v, vi)) { v = ov; vi = oi; }
            }
            if (vi < 0) break;
            if (lane == 0) atomicOr(&mrow[vi], 1u << g);
            if (i4 == vi) { v4 = -1.f; i4 = -1; }
        }
    }
}

// ------- Kernel 3: fg-only losses + fused final reduction (last-block pattern) -------
__global__ __launch_bounds__(256) void k_loss(
        const float* __restrict__ targets,
        const float* __restrict__ pd_boxes, const float* __restrict__ logZ,
        const float* __restrict__ amax, const unsigned int* __restrict__ mask,
        const float* __restrict__ p0, const float* __restrict__ p1, const float* __restrict__ p2,
        float* __restrict__ partial, const float* __restrict__ partial_prep,
        unsigned int* __restrict__ done, float* __restrict__ out) {
    int idx = blockIdx.x * 256 + threadIdx.x;
    float bce_s = 0.f, bbox_s = 0.f, dfl_s = 0.f, fg_s = 0.f;
    if (idx < NBA) {
        unsigned int m = mask[idx];
        if (m != 0u) {
            int b = idx / A_TOT, a = idx % A_TOT;
            int lvl, ai, w_, hw; float s;
            anchor_decode(a, lvl, ai, w_, hw, s);
            const float* p = (lvl == 0) ? p0 : ((lvl == 1) ? p1 : p2);
            const float* base = p + (size_t)b * 70 * hw + ai;
            float ax = ((ai % w_) + 0.5f) * s, ay = ((ai / w_) + 0.5f) * s;
            float4 box = ((const float4*)pd_boxes)[idx];
            int gidx;
            if (__popc(m) > 1) {
                float best = -1.f; gidx = 0;
                for (int g = 0; g < G; ++g) {
                    const float* tg = targets + ((size_t)b * G + g) * 6;
                    int labg = (int)tg[1];
                    float al = align_from(tg, base[(size_t)(64 + labg) * hw], box, ax, ay);
                    if (al > best) { best = al; gidx = g; }
                }
            } else {
                gidx = __ffs(m) - 1;
            }
            const float* t = targets + ((size_t)b * G + gidx) * 6;
            int lab = (int)t[1];
            float logit = base[(size_t)(64 + lab) * hw];
            float al = align_from(t, logit, box, ax, ay);
            float cx = t[2] * 640.f, cy = t[3] * 640.f;
            float hwd = t[4] * 320.f, hh = t[5] * 320.f;
            float tbx1 = cx - hwd, tby1 = cy - hh, tbx2 = cx + hwd, tby2 = cy + hh;
            const float eps = 1e-7f;
            float x1 = fmaxf(box.x, tbx1), y1 = fmaxf(box.y, tby1);
            float x2 = fminf(box.z, tbx2), y2 = fminf(box.w, tby2);
            float inter = fmaxf(x2 - x1, 0.f) * fmaxf(y2 - y1, 0.f);
            float w1 = fmaxf(box.z - box.x, eps), h1 = fmaxf(box.w - box.y, eps);
            float w2 = fmaxf(tbx2 - tbx1, eps), h2 = fmaxf(tby2 - tby1, eps);
            float uni = w1 * h1 + w2 * h2 - inter + eps;
            float iou = inter / uni;
            float iou_fg = fmaxf(iou, 0.f);
            float sval = (al / (amax[b * G + gidx] + 1e-9f)) * iou_fg;
            bce_s = -logit * sval;          // BCE correction for target!=0
            fg_s = 1.f;
            // CIoU
            float cw = fmaxf(box.z, tbx2) - fminf(box.x, tbx1);
            float ch = fmaxf(box.w, tby2) - fminf(box.y, tby1);
            float c2 = cw * cw + ch * ch + eps;
            float dx = box.x + box.z - tbx1 - tbx2;
            float dy = box.y + box.w - tby1 - tby2;
            float rho2 = (dx * dx + dy * dy) * 0.25f;
            float dv = atanf(w2 / h2) - atanf(w1 / h1);
            float v = 0.40528473f * dv * dv;            // 4/pi^2
            float alpha = v / (v - iou + (1.f + eps));
            float ciou = iou - (rho2 / c2 + v * alpha);
            bbox_s = 1.f - ciou;
            // DFL
            float4 lzv = ((const float4*)logZ)[idx];
            float lz[4] = {lzv.x, lzv.y, lzv.z, lzv.w};
            float lt[4] = {(ax - tbx1) / s, (ay - tby1) / s, (tbx2 - ax) / s, (tby2 - ay) / s};
            #pragma unroll
            for (int sd = 0; sd < 4; ++sd) {
                float d = fminf(fmaxf(lt[sd], 0.f), (float)RM - 1.01f);
                int tl = (int)d;
                float wl = (float)(tl + 1) - d;
                float wr = d - (float)tl;
                float xl = base[(size_t)(sd * RM + tl) * hw];
                float xr = base[(size_t)(sd * RM + tl + 1) * hw];
                dfl_s += (lz[sd] - xl) * wl + (lz[sd] - xr) * wr;
            }
        }
    }
    __shared__ float part[4][4];
    int lane = threadIdx.x & 63, wv = threadIdx.x >> 6;
    #pragma unroll
    for (int off = 32; off > 0; off >>= 1) {
        bce_s  += __shfl_down(bce_s,  off);
        bbox_s += __shfl_down(bbox_s, off);
        dfl_s  += __shfl_down(dfl_s,  off);
        fg_s   += __shfl_down(fg_s,   off);
    }
    if (lane == 0) {
        part[wv][0] = bce_s; part[wv][1] = bbox_s;
        part[wv][2] = dfl_s; part[wv][3] = fg_s;
    }
    __syncthreads();
    if (threadIdx.x == 0) {
        float s0 = 0.f, s1 = 0.f, s2 = 0.f, s3 = 0.f;
        for (int i = 0; i < 4; ++i) {
            s0 += part[i][0]; s1 += part[i][1]; s2 += part[i][2]; s3 += part[i][3];
        }
        ((float4*)partial)[blockIdx.x] = make_float4(s0, s1, s2, s3);
    }

    // ---- fused final reduction: last block to arrive does it ----
    __shared__ int amlast;
    if (threadIdx.x == 0) {
        __threadfence();                         // release: partial visible before ticket
        unsigned int old = atomicAdd(done, 1u);
        amlast = (old == (unsigned int)(NBLK_LOSS - 1));
    }
    __syncthreads();
    if (!amlast) return;
    if (threadIdx.x == 0) *done = 0u;            // reset for next graph replay
    __threadfence();                             // acquire: invalidate stale L2 lines

    double a0 = 0., a1 = 0., a2 = 0., a3 = 0.;
    for (int i = threadIdx.x; i < NBLK_LOSS; i += 256) {
        float4 pp = ((const float4*)partial)[i];
        a0 += pp.x; a1 += pp.y; a2 += pp.z; a3 += pp.w;
    }
    for (int i = threadIdx.x; i < NBLK_PREP; i += 256)
        a0 += partial_prep[i];
    #pragma unroll
    for (int off = 32; off > 0; off >>= 1) {
        a0 += __shfl_down(a0, off);
        a1 += __shfl_down(a1, off);
        a2 += __shfl_down(a2, off);
        a3 += __shfl_down(a3, off);
    }
    __shared__ double dpart[4][4];
    if (lane == 0) { dpart[wv][0] = a0; dpart[wv][1] = a1; dpart[wv][2] = a2; dpart[wv][3] = a3; }
    __syncthreads();
    if (threadIdx.x == 0) {
        double bce = 0., bbox = 0., dfl = 0., fgc = 0.;
        for (int i = 0; i < 4; ++i) {
            bce += dpart[i][0]; bbox += dpart[i][1]; dfl += dpart[i][2]; fgc += dpart[i][3];
        }
        double l_cls = bce / (double)A_TOT;
        double np_ = fmax(fgc, 1.0);
        double l_bbox = 7.5 * bbox / np_;
        double l_dfl = 1.5 * dfl / np_;
        out[0] = (float)(l_cls + l_bbox + l_dfl);
        out[1] = (float)l_cls;
        out[2] = (float)l_bbox;
        out[3] = 0.f;
        out[4] = (float)l_dfl;
    }
}

extern "C" void kernel_launch(void* const* d_in, const int* in_sizes, int n_in,
                              void* d_out, int out_size, void* d_ws, size_t ws_size,
                              hipStream_t stream) {
    const float* p0 = (const float*)d_in[0];
    const float* p1 = (const float*)d_in[1];
    const float* p2 = (const float*)d_in[2];
    const float* targets = (const float*)d_in[3];
    float* out = (float*)d_out;

    char* ws = (char*)d_ws;
    size_t off = 0;
    float* pd_boxes = (float*)(ws + off); off += (size_t)NBA * 4 * sizeof(float);
    float* logZ     = (float*)(ws + off); off += (size_t)NBA * 4 * sizeof(float);
    float* amax     = (float*)(ws + off); off += (size_t)BSZ * G * sizeof(float);
    unsigned int* mask = (unsigned int*)(ws + off); off += (size_t)NBA * sizeof(unsigned int);
    float* partial  = (float*)(ws + off); off += (size_t)NBLK_LOSS * 4 * sizeof(float);
    float* partial_prep = (float*)(ws + off); off += (size_t)NBLK_PREP * sizeof(float);
    unsigned int* done = (unsigned int*)(ws + off); off += sizeof(unsigned int);

    k_prep<<<NBLK_PREP, 256, 0, stream>>>(p0, p1, p2, pd_boxes, logZ, mask, partial_prep, done);
    k_align<<<BSZ * G, 256, 0, stream>>>(targets, pd_boxes, p0, p1, p2, amax, mask);
    k_loss<<<NBLK_LOSS, 256, 0, stream>>>(targets, pd_boxes, logZ, amax, mask,
                                          p0, p1, p2, partial, partial_prep, done, out);
}

// Round 2
// 143.535 us; speedup vs baseline: 1.1228x; 1.1228x over previous
//
#include <hip/hip_runtime.h>
#include <math.h>

#define NC 6
#define RM 16
#define TOPK 10
#define BSZ 32
#define G 20
#define A_TOT 8400
#define NBA (BSZ * A_TOT)
#define NBLK_PREP (NBA / 256)          /* 1050 */
#define NBLK_LOSS ((NBA + 255) / 256)  /* 1050 */
#define MAXCAND 1024

__device__ __forceinline__ void anchor_decode(int a, int& lvl, int& ai, int& w, int& hw, float& s) {
    if (a < 6400)      { lvl = 0; ai = a;        w = 80; hw = 6400; s = 8.f; }
    else if (a < 8000) { lvl = 1; ai = a - 6400; w = 40; hw = 1600; s = 16.f; }
    else               { lvl = 2; ai = a - 8000; w = 20; hw = 400;  s = 32.f; }
}

// task-aligned metric for one (gt, anchor) pair; returns 0 if anchor center not in gt
__device__ __forceinline__ float align_from(const float* __restrict__ trow, float logit,
                                            float4 box, float ax, float ay) {
    float cx = trow[2] * 640.f, cy = trow[3] * 640.f;
    float hwd = trow[4] * 320.f, hh = trow[5] * 320.f;
    float gx1 = cx - hwd, gy1 = cy - hh, gx2 = cx + hwd, gy2 = cy + hh;
    float mn = fminf(fminf(ax - gx1, ay - gy1), fminf(gx2 - ax, gy2 - ay));
    if (mn <= 1e-9f) return 0.f;
    const float eps = 1e-7f;
    float x1 = fmaxf(gx1, box.x), y1 = fmaxf(gy1, box.y);
    float x2 = fminf(gx2, box.z), y2 = fminf(gy2, box.w);
    float inter = fmaxf(x2 - x1, 0.f) * fmaxf(y2 - y1, 0.f);
    float gw = fmaxf(gx2 - gx1, eps), gh = fmaxf(gy2 - gy1, eps);
    float w2 = fmaxf(box.z - box.x, eps), h2 = fmaxf(box.w - box.y, eps);
    float uni = gw * gh + w2 * h2 - inter + eps;
    float iou = inter / uni;
    float sc = 1.f / (1.f + __expf(-logit));
    float i2 = iou * iou;
    return sqrtf(sc) * (i2 * i2 * i2);
}

// ------- Kernel 1: decode boxes, logZ, base BCE, zero mask -------
// Quad-split: 4 threads per quad of consecutive anchors; thread sd does side sd's
// 16-channel single-pass softmax. 4x4 side<->anchor transpose done IN-REGISTER
// via __shfl_xor (masks 1,2): no LDS arrays for it, zero LDS bank conflicts.
__global__ __launch_bounds__(256) void k_prep(
        const float* __restrict__ p0, const float* __restrict__ p1, const float* __restrict__ p2,
        float* __restrict__ pd_boxes, float* __restrict__ logZ,
        unsigned int* __restrict__ mask, float* __restrict__ partial_prep) {
    int tid = blockIdx.x * 256 + threadIdx.x;
    int q = tid >> 2;           // quad index
    int sd = tid & 3;           // side handled by this thread
    int idx4 = q * 4;
    int b = idx4 / A_TOT, a4 = idx4 % A_TOT;
    int lvl, ai, w, hw; float s;
    anchor_decode(a4, lvl, ai, w, hw, s);
    const float* p = (lvl == 0) ? p0 : ((lvl == 1) ? p1 : p2);
    const float* base = p + (size_t)b * 70 * hw + ai;

    float4 se = make_float4(0, 0, 0, 0), sk = make_float4(0, 0, 0, 0);
    #pragma unroll
    for (int k = 0; k < RM; ++k) {
        float4 v = *(const float4*)(base + (size_t)(sd * RM + k) * hw);
        float fk = (float)k;
        float ex = __expf(v.x); se.x += ex; sk.x += ex * fk;
        float ey = __expf(v.y); se.y += ey; sk.y += ey * fk;
        float ez = __expf(v.z); se.z += ez; sk.z += ez * fk;
        float ew = __expf(v.w); se.w += ew; sk.w += ew * fk;
    }
    // row (this thread): side sd's dist / logZ for the quad's 4 anchors
    float d0 = sk.x / se.x, d1 = sk.y / se.y, d2 = sk.z / se.z, d3 = sk.w / se.w;
    float z0 = __logf(se.x), z1 = __logf(se.y), z2 = __logf(se.z), z3 = __logf(se.w);

    // in-wave 4x4 transpose within each quad (lanes 4q..4q+3): after this,
    // thread sd holds all 4 sides of anchor (quad, j=sd).
    bool lo = (sd & 1) == 0, hi = (sd & 2) == 0;
    // dist
    float ea0 = __shfl_xor(d0, 1), ea1 = __shfl_xor(d1, 1), ea2 = __shfl_xor(d2, 1), ea3 = __shfl_xor(d3, 1);
    float na0 = lo ? d0 : ea1, na1 = lo ? ea0 : d1, na2 = lo ? d2 : ea3, na3 = lo ? ea2 : d3;
    float fa0 = __shfl_xor(na0, 2), fa1 = __shfl_xor(na1, 2), fa2 = __shfl_xor(na2, 2), fa3 = __shfl_xor(na3, 2);
    float ma0 = hi ? na0 : fa2, ma1 = hi ? na1 : fa3, ma2 = hi ? fa0 : na2, ma3 = hi ? fa1 : na3;
    // logZ
    float za0 = __shfl_xor(z0, 1), za1 = __shfl_xor(z1, 1), za2 = __shfl_xor(z2, 1), za3 = __shfl_xor(z3, 1);
    float zb0 = lo ? z0 : za1, zb1 = lo ? za0 : z1, zb2 = lo ? z2 : za3, zb3 = lo ? za2 : z3;
    float zc0 = __shfl_xor(zb0, 2), zc1 = __shfl_xor(zb1, 2), zc2 = __shfl_xor(zb2, 2), zc3 = __shfl_xor(zb3, 2);
    float zd0 = hi ? zb0 : zc2, zd1 = hi ? zb1 : zc3, zd2 = hi ? zc0 : zb2, zd3 = hi ? zc1 : zb3;

    float ax = ((float)(ai % w + sd) + 0.5f) * s;
    float ay = ((float)(ai / w) + 0.5f) * s;
    ((float4*)pd_boxes)[tid] = make_float4(ax - ma0 * s, ay - ma1 * s, ax + ma2 * s, ay + ma3 * s);
    ((float4*)logZ)[tid] = make_float4(zd0, zd1, zd2, zd3);
    mask[tid] = 0u;

    // base BCE (target=0 term) for class channels 64+sd (+68+sd for sd<2)
    float bce = 0.f;
    {
        float4 x = *(const float4*)(base + (size_t)(64 + sd) * hw);
        bce += fmaxf(x.x, 0.f) + __logf(1.f + __expf(-fabsf(x.x)));
        bce += fmaxf(x.y, 0.f) + __logf(1.f + __expf(-fabsf(x.y)));
        bce += fmaxf(x.z, 0.f) + __logf(1.f + __expf(-fabsf(x.z)));
        bce += fmaxf(x.w, 0.f) + __logf(1.f + __expf(-fabsf(x.w)));
        if (sd < 2) {
            float4 y = *(const float4*)(base + (size_t)(68 + sd) * hw);
            bce += fmaxf(y.x, 0.f) + __logf(1.f + __expf(-fabsf(y.x)));
            bce += fmaxf(y.y, 0.f) + __logf(1.f + __expf(-fabsf(y.y)));
            bce += fmaxf(y.z, 0.f) + __logf(1.f + __expf(-fabsf(y.z)));
            bce += fmaxf(y.w, 0.f) + __logf(1.f + __expf(-fabsf(y.w)));
        }
    }

    // block reduce bce
    __shared__ float part[4];
    int lane = threadIdx.x & 63, wv = threadIdx.x >> 6;
    #pragma unroll
    for (int off = 32; off > 0; off >>= 1) bce += __shfl_down(bce, off);
    if (lane == 0) part[wv] = bce;
    __syncthreads();
    if (threadIdx.x == 0)
        partial_prep[blockIdx.x] = part[0] + part[1] + part[2] + part[3];
}

// prefer higher value; on tie prefer LOWER index (matches jax.lax.top_k)
__device__ __forceinline__ bool cand_better(float av, int ai_, float bv, int bi_) {
    if (av > bv) return true;
    if (av < bv) return false;
    if (ai_ < 0) return false;
    if (bi_ < 0) return true;
    return ai_ < bi_;
}

// ------- Kernel 2: per-(b,g) bounded cell scan + top-10 -> mask bits, row max -------
// Per-wave barrier-free top-10 via __shfl_xor butterflies, then a single wave-0
// merge of the 4x10 survivors. amax comes from the scan phase. 3 barriers/block.
__global__ __launch_bounds__(256) void k_align(
        const float* __restrict__ targets,
        const float* __restrict__ pd_boxes,
        const float* __restrict__ p0, const float* __restrict__ p1, const float* __restrict__ p2,
        float* __restrict__ amax, unsigned int* __restrict__ mask) {
    __shared__ float cval[MAXCAND];
    __shared__ int   cidx[MAXCAND];
    __shared__ int   cnt_s;
    __shared__ float wtv[4][TOPK];
    __shared__ int   wti[4][TOPK];
    __shared__ float redf[4];

    int bg = blockIdx.x;
    int b = bg / G;
    int g = bg % G;
    const float* t = targets + (size_t)bg * 6;
    int lab = (int)t[1];
    const float* cb[3];
    cb[0] = p0 + (size_t)b * 70 * 6400 + (size_t)(64 + lab) * 6400;
    cb[1] = p1 + (size_t)b * 70 * 1600 + (size_t)(64 + lab) * 1600;
    cb[2] = p2 + (size_t)b * 70 * 400  + (size_t)(64 + lab) * 400;
    const float4* pb = (const float4*)pd_boxes + (size_t)b * A_TOT;

    float cx = t[2] * 640.f, cy = t[3] * 640.f;
    float hwd = t[4] * 320.f, hh = t[5] * 320.f;
    float gx1 = cx - hwd, gy1 = cy - hh, gx2 = cx + hwd, gy2 = cy + hh;

    const float sv3[3] = {8.f, 16.f, 32.f};
    const int   wv3[3] = {80, 40, 20};
    const int   ov3[3] = {0, 6400, 8000};
    int x0[3], y0[3], nx[3], ncell[3];
    int ntot = 0;
    #pragma unroll
    for (int l = 0; l < 3; ++l) {
        float s = sv3[l]; int w = wv3[l];
        int xa = max(0, (int)floorf(gx1 / s - 0.5f));
        int xb = min(w - 1, (int)ceilf(gx2 / s - 0.5f));
        int ya = max(0, (int)floorf(gy1 / s - 0.5f));
        int yb = min(w - 1, (int)ceilf(gy2 / s - 0.5f));
        x0[l] = xa; y0[l] = ya;
        nx[l] = max(0, xb - xa + 1);
        int nyl = max(0, yb - ya + 1);
        ncell[l] = nx[l] * nyl;
        ntot += ncell[l];
    }

    if (threadIdx.x == 0) cnt_s = 0;
    __syncthreads();

    float lmax = -1.f;
    for (int i = threadIdx.x; i < ntot; i += 256) {
        int l = 0, loc = i;
        if (loc >= ncell[0]) { loc -= ncell[0]; l = 1; }
        if (l == 1 && loc >= ncell[1]) { loc -= ncell[1]; l = 2; }
        int iy = loc / nx[l], ix = loc % nx[l];
        ix += x0[l]; iy += y0[l];
        float s = sv3[l]; int w = wv3[l];
        float ax = ((float)ix + 0.5f) * s, ay = ((float)iy + 0.5f) * s;
        int a = ov3[l] + iy * w + ix;
        float logit = cb[l][iy * w + ix];
        float al = align_from(t, logit, pb[a], ax, ay);
        if (al > 0.f) {
            lmax = fmaxf(lmax, al);
            int p = atomicAdd(&cnt_s, 1);
            if (p < MAXCAND) { cval[p] = al; cidx[p] = a; }
        }
    }
    int lane = threadIdx.x & 63, wv = threadIdx.x >> 6;
    #pragma unroll
    for (int off = 32; off > 0; off >>= 1) lmax = fmaxf(lmax, __shfl_xor(lmax, off));
    if (lane == 0) redf[wv] = lmax;
    __syncthreads();   // covers redf AND cval/cidx visibility
    if (threadIdx.x == 0)
        amax[bg] = fmaxf(fmaxf(fmaxf(redf[0], redf[1]), fmaxf(redf[2], redf[3])), 0.f);

    int cnt = min(cnt_s, MAXCAND);
    float mv[MAXCAND / 256];
    int   mi[MAXCAND / 256];
    #pragma unroll
    for (int r = 0; r < MAXCAND / 256; ++r) {
        int p = threadIdx.x + r * 256;
        mv[r] = (p < cnt) ? cval[p] : -1.f;
        mi[r] = (p < cnt) ? cidx[p] : -1;
    }

    // per-wave top-10: no barriers, butterfly gives every lane the winner
    for (int it = 0; it < TOPK; ++it) {
        float v = -1.f; int vi = -1;
        #pragma unroll
        for (int r = 0; r < MAXCAND / 256; ++r)
            if (cand_better(mv[r], mi[r], v, vi)) { v = mv[r]; vi = mi[r]; }
        #pragma unroll
        for (int off = 1; off < 64; off <<= 1) {
            float ov = __shfl_xor(v, off);
            int   oi = __shfl_xor(vi, off);
            if (cand_better(ov, oi, v, vi)) { v = ov; vi = oi; }
        }
        if (vi < 0) {
            if (lane == 0)
                for (int j = it; j < TOPK; ++j) { wtv[wv][j] = -1.f; wti[wv][j] = -1; }
            break;
        }
        if (lane == 0) { wtv[wv][it] = v; wti[wv][it] = vi; }
        #pragma unroll
        for (int r = 0; r < MAXCAND / 256; ++r)
            if (mi[r] == vi) { mv[r] = -1.f; mi[r] = -1; }
    }
    __syncthreads();

    // wave 0 merges the 40 survivors (global top-10 is a subset of per-part top-10s)
    if (wv == 0) {
        float v4 = -1.f; int i4 = -1;
        if (lane < 4 * TOPK) { v4 = wtv[lane / TOPK][lane % TOPK]; i4 = wti[lane / TOPK][lane % TOPK]; }
        unsigned int* mrow = mask + (size_t)b * A_TOT;
        for (int it = 0; it < TOPK; ++it) {
            float v = v4; int vi = i4;
            #pragma unroll
            for (int off = 1; off < 64; off <<= 1) {
                float ov = __shfl_xor(v, off);
                int   oi = __shfl_xor(vi, off);
                if (cand_better(ov, oi, v, vi)) { v = ov; vi = oi; }
            }
            if (vi < 0) break;
            if (lane == 0) atomicOr(&mrow[vi], 1u << g);
            if (i4 == vi) { v4 = -1.f; i4 = -1; }
        }
    }
}

// ------- Kernel 3: fg-only losses (1 anchor/thread, 1050 blocks), per-block partials -------
__global__ __launch_bounds__(256) void k_loss(
        const float* __restrict__ targets,
        const float* __restrict__ pd_boxes, const float* __restrict__ logZ,
        const float* __restrict__ amax, const unsigned int* __restrict__ mask,
        const float* __restrict__ p0, const float* __restrict__ p1, const float* __restrict__ p2,
        float* __restrict__ partial) {
    int idx = blockIdx.x * 256 + threadIdx.x;
    float bce_s = 0.f, bbox_s = 0.f, dfl_s = 0.f, fg_s = 0.f;
    if (idx < NBA) {
        unsigned int m = mask[idx];
        if (m != 0u) {
            int b = idx / A_TOT, a = idx % A_TOT;
            int lvl, ai, w_, hw; float s;
            anchor_decode(a, lvl, ai, w_, hw, s);
            const float* p = (lvl == 0) ? p0 : ((lvl == 1) ? p1 : p2);
            const float* base = p + (size_t)b * 70 * hw + ai;
            float ax = ((ai % w_) + 0.5f) * s, ay = ((ai / w_) + 0.5f) * s;
            float4 box = ((const float4*)pd_boxes)[idx];
            int gidx;
            if (__popc(m) > 1) {
                float best = -1.f; gidx = 0;
                for (int g = 0; g < G; ++g) {
                    const float* tg = targets + ((size_t)b * G + g) * 6;
                    int labg = (int)tg[1];
                    float al = align_from(tg, base[(size_t)(64 + labg) * hw], box, ax, ay);
                    if (al > best) { best = al; gidx = g; }
                }
            } else {
                gidx = __ffs(m) - 1;
            }
            const float* t = targets + ((size_t)b * G + gidx) * 6;
            int lab = (int)t[1];
            float logit = base[(size_t)(64 + lab) * hw];
            float al = align_from(t, logit, box, ax, ay);
            float cx = t[2] * 640.f, cy = t[3] * 640.f;
            float hwd = t[4] * 320.f, hh = t[5] * 320.f;
            float tbx1 = cx - hwd, tby1 = cy - hh, tbx2 = cx + hwd, tby2 = cy + hh;
            const float eps = 1e-7f;
            float x1 = fmaxf(box.x, tbx1), y1 = fmaxf(box.y, tby1);
            float x2 = fminf(box.z, tbx2), y2 = fminf(box.w, tby2);
            float inter = fmaxf(x2 - x1, 0.f) * fmaxf(y2 - y1, 0.f);
            float w1 = fmaxf(box.z - box.x, eps), h1 = fmaxf(box.w - box.y, eps);
            float w2 = fmaxf(tbx2 - tbx1, eps), h2 = fmaxf(tby2 - tby1, eps);
            float uni = w1 * h1 + w2 * h2 - inter + eps;
            float iou = inter / uni;
            float iou_fg = fmaxf(iou, 0.f);
            float sval = (al / (amax[b * G + gidx] + 1e-9f)) * iou_fg;
            bce_s = -logit * sval;          // BCE correction for target!=0
            fg_s = 1.f;
            // CIoU
            float cw = fmaxf(box.z, tbx2) - fminf(box.x, tbx1);
            float ch = fmaxf(box.w, tby2) - fminf(box.y, tby1);
            float c2 = cw * cw + ch * ch + eps;
            float dx = box.x + box.z - tbx1 - tbx2;
            float dy = box.y + box.w - tby1 - tby2;
            float rho2 = (dx * dx + dy * dy) * 0.25f;
            float dv = atanf(w2 / h2) - atanf(w1 / h1);
            float v = 0.40528473f * dv * dv;            // 4/pi^2
            float alpha = v / (v - iou + (1.f + eps));
            float ciou = iou - (rho2 / c2 + v * alpha);
            bbox_s = 1.f - ciou;
            // DFL
            float4 lzv = ((const float4*)logZ)[idx];
            float lz[4] = {lzv.x, lzv.y, lzv.z, lzv.w};
            float lt[4] = {(ax - tbx1) / s, (ay - tby1) / s, (tbx2 - ax) / s, (tby2 - ay) / s};
            #pragma unroll
            for (int sd = 0; sd < 4; ++sd) {
                float d = fminf(fmaxf(lt[sd], 0.f), (float)RM - 1.01f);
                int tl = (int)d;
                float wl = (float)(tl + 1) - d;
                float wr = d - (float)tl;
                float xl = base[(size_t)(sd * RM + tl) * hw];
                float xr = base[(size_t)(sd * RM + tl + 1) * hw];
                dfl_s += (lz[sd] - xl) * wl + (lz[sd] - xr) * wr;
            }
        }
    }
    __shared__ float part[4][4];
    int lane = threadIdx.x & 63, wv = threadIdx.x >> 6;
    #pragma unroll
    for (int off = 32; off > 0; off >>= 1) {
        bce_s  += __shfl_down(bce_s,  off);
        bbox_s += __shfl_down(bbox_s, off);
        dfl_s  += __shfl_down(dfl_s,  off);
        fg_s   += __shfl_down(fg_s,   off);
    }
    if (lane == 0) {
        part[wv][0] = bce_s; part[wv][1] = bbox_s;
        part[wv][2] = dfl_s; part[wv][3] = fg_s;
    }
    __syncthreads();
    if (threadIdx.x == 0) {
        float s0 = 0.f, s1 = 0.f, s2 = 0.f, s3 = 0.f;
        for (int i = 0; i < 4; ++i) {
            s0 += part[i][0]; s1 += part[i][1]; s2 += part[i][2]; s3 += part[i][3];
        }
        ((float4*)partial)[blockIdx.x] = make_float4(s0, s1, s2, s3);
    }
}

// ------- Kernel 4: reduce partials, combine -------
__global__ __launch_bounds__(256) void k_final(const float* __restrict__ partial,
                                               const float* __restrict__ partial_prep,
                                               float* __restrict__ out) {
    double s0 = 0., s1 = 0., s2 = 0., s3 = 0.;
    for (int i = threadIdx.x; i < NBLK_LOSS; i += 256) {
        float4 p = ((const float4*)partial)[i];
        s0 += p.x; s1 += p.y; s2 += p.z; s3 += p.w;
    }
    for (int i = threadIdx.x; i < NBLK_PREP; i += 256)
        s0 += partial_prep[i];
    #pragma unroll
    for (int off = 32; off > 0; off >>= 1) {
        s0 += __shfl_down(s0, off);
        s1 += __shfl_down(s1, off);
        s2 += __shfl_down(s2, off);
        s3 += __shfl_down(s3, off);
    }
    __shared__ double part[4][4];
    int lane = threadIdx.x & 63, wv = threadIdx.x >> 6;
    if (lane == 0) { part[wv][0] = s0; part[wv][1] = s1; part[wv][2] = s2; part[wv][3] = s3; }
    __syncthreads();
    if (threadIdx.x == 0) {
        double bce = 0., bbox = 0., dfl = 0., fgc = 0.;
        for (int i = 0; i < 4; ++i) {
            bce += part[i][0]; bbox += part[i][1]; dfl += part[i][2]; fgc += part[i][3];
        }
        double l_cls = bce / (double)A_TOT;
        double np_ = fmax(fgc, 1.0);
        double l_bbox = 7.5 * bbox / np_;
        double l_dfl = 1.5 * dfl / np_;
        out[0] = (float)(l_cls + l_bbox + l_dfl);
        out[1] = (float)l_cls;
        out[2] = (float)l_bbox;
        out[3] = 0.f;
        out[4] = (float)l_dfl;
    }
}

extern "C" void kernel_launch(void* const* d_in, const int* in_sizes, int n_in,
                              void* d_out, int out_size, void* d_ws, size_t ws_size,
                              hipStream_t stream) {
    const float* p0 = (const float*)d_in[0];
    const float* p1 = (const float*)d_in[1];
    const float* p2 = (const float*)d_in[2];
    const float* targets = (const float*)d_in[3];
    float* out = (float*)d_out;

    char* ws = (char*)d_ws;
    size_t off = 0;
    float* pd_boxes = (float*)(ws + off); off += (size_t)NBA * 4 * sizeof(float);
    float* logZ     = (float*)(ws + off); off += (size_t)NBA * 4 * sizeof(float);
    float* amax     = (float*)(ws + off); off += (size_t)BSZ * G * sizeof(float);
    unsigned int* mask = (unsigned int*)(ws + off); off += (size_t)NBA * sizeof(unsigned int);
    float* partial  = (float*)(ws + off); off += (size_t)NBLK_LOSS * 4 * sizeof(float);
    float* partial_prep = (float*)(ws + off); off += (size_t)NBLK_PREP * sizeof(float);

    k_prep<<<NBLK_PREP, 256, 0, stream>>>(p0, p1, p2, pd_boxes, logZ, mask, partial_prep);
    k_align<<<BSZ * G, 256, 0, stream>>>(targets, pd_boxes, p0, p1, p2, amax, mask);
    k_loss<<<NBLK_LOSS, 256, 0, stream>>>(targets, pd_boxes, logZ, amax, mask,
                                          p0, p1, p2, partial);
    k_final<<<1, 256, 0, stream>>>(partial, partial_prep, out);
}

// Round 3
// 138.015 us; speedup vs baseline: 1.1678x; 1.0400x over previous
//
#include <hip/hip_runtime.h>
#include <math.h>

#define NC 6
#define RM 16
#define TOPK 10
#define BSZ 32
#define G 20
#define A_TOT 8400
#define NBA (BSZ * A_TOT)
#define NBLK_PREP (NBA / 256)          /* 1050 */
#define NBLK_LOSS ((NBA + 255) / 256)  /* 1050 */
#define MAXCAND 1024

__device__ __forceinline__ void anchor_decode(int a, int& lvl, int& ai, int& w, int& hw, float& s) {
    if (a < 6400)      { lvl = 0; ai = a;        w = 80; hw = 6400; s = 8.f; }
    else if (a < 8000) { lvl = 1; ai = a - 6400; w = 40; hw = 1600; s = 16.f; }
    else               { lvl = 2; ai = a - 8000; w = 20; hw = 400;  s = 32.f; }
}

// task-aligned metric for one (gt, anchor) pair; returns 0 if anchor center not in gt
__device__ __forceinline__ float align_from(const float* __restrict__ trow, float logit,
                                            float4 box, float ax, float ay) {
    float cx = trow[2] * 640.f, cy = trow[3] * 640.f;
    float hwd = trow[4] * 320.f, hh = trow[5] * 320.f;
    float gx1 = cx - hwd, gy1 = cy - hh, gx2 = cx + hwd, gy2 = cy + hh;
    float mn = fminf(fminf(ax - gx1, ay - gy1), fminf(gx2 - ax, gy2 - ay));
    if (mn <= 1e-9f) return 0.f;
    const float eps = 1e-7f;
    float x1 = fmaxf(gx1, box.x), y1 = fmaxf(gy1, box.y);
    float x2 = fminf(gx2, box.z), y2 = fminf(gy2, box.w);
    float inter = fmaxf(x2 - x1, 0.f) * fmaxf(y2 - y1, 0.f);
    float gw = fmaxf(gx2 - gx1, eps), gh = fmaxf(gy2 - gy1, eps);
    float w2 = fmaxf(box.z - box.x, eps), h2 = fmaxf(box.w - box.y, eps);
    float uni = gw * gh + w2 * h2 - inter + eps;
    float iou = inter / uni;
    float sc = 1.f / (1.f + __expf(-logit));
    float i2 = iou * iou;
    return sqrtf(sc) * (i2 * i2 * i2);
}

// ------- Kernel 1: decode boxes, logZ, base BCE, zero mask+packed -------
// Quad-split: 4 threads per quad of consecutive anchors; thread sd does side sd's
// 16-channel single-pass softmax. 4x4 side<->anchor transpose in-register via
// __shfl_xor (masks 1,2): zero LDS bank conflicts.
__global__ __launch_bounds__(256) void k_prep(
        const float* __restrict__ p0, const float* __restrict__ p1, const float* __restrict__ p2,
        float* __restrict__ pd_boxes, float* __restrict__ logZ,
        unsigned int* __restrict__ mask, unsigned long long* __restrict__ packed,
        float* __restrict__ partial_prep) {
    int tid = blockIdx.x * 256 + threadIdx.x;
    int q = tid >> 2;           // quad index
    int sd = tid & 3;           // side handled by this thread
    int idx4 = q * 4;
    int b = idx4 / A_TOT, a4 = idx4 % A_TOT;
    int lvl, ai, w, hw; float s;
    anchor_decode(a4, lvl, ai, w, hw, s);
    const float* p = (lvl == 0) ? p0 : ((lvl == 1) ? p1 : p2);
    const float* base = p + (size_t)b * 70 * hw + ai;

    float4 se = make_float4(0, 0, 0, 0), sk = make_float4(0, 0, 0, 0);
    #pragma unroll
    for (int k = 0; k < RM; ++k) {
        float4 v = *(const float4*)(base + (size_t)(sd * RM + k) * hw);
        float fk = (float)k;
        float ex = __expf(v.x); se.x += ex; sk.x += ex * fk;
        float ey = __expf(v.y); se.y += ey; sk.y += ey * fk;
        float ez = __expf(v.z); se.z += ez; sk.z += ez * fk;
        float ew = __expf(v.w); se.w += ew; sk.w += ew * fk;
    }
    // row (this thread): side sd's dist / logZ for the quad's 4 anchors
    float d0 = sk.x / se.x, d1 = sk.y / se.y, d2 = sk.z / se.z, d3 = sk.w / se.w;
    float z0 = __logf(se.x), z1 = __logf(se.y), z2 = __logf(se.z), z3 = __logf(se.w);

    // in-wave 4x4 transpose within each quad (lanes 4q..4q+3): after this,
    // thread sd holds all 4 sides of anchor (quad, j=sd).
    bool lo = (sd & 1) == 0, hi = (sd & 2) == 0;
    // dist
    float ea0 = __shfl_xor(d0, 1), ea1 = __shfl_xor(d1, 1), ea2 = __shfl_xor(d2, 1), ea3 = __shfl_xor(d3, 1);
    float na0 = lo ? d0 : ea1, na1 = lo ? ea0 : d1, na2 = lo ? d2 : ea3, na3 = lo ? ea2 : d3;
    float fa0 = __shfl_xor(na0, 2), fa1 = __shfl_xor(na1, 2), fa2 = __shfl_xor(na2, 2), fa3 = __shfl_xor(na3, 2);
    float ma0 = hi ? na0 : fa2, ma1 = hi ? na1 : fa3, ma2 = hi ? fa0 : na2, ma3 = hi ? fa1 : na3;
    // logZ
    float za0 = __shfl_xor(z0, 1), za1 = __shfl_xor(z1, 1), za2 = __shfl_xor(z2, 1), za3 = __shfl_xor(z3, 1);
    float zb0 = lo ? z0 : za1, zb1 = lo ? za0 : z1, zb2 = lo ? z2 : za3, zb3 = lo ? za2 : z3;
    float zc0 = __shfl_xor(zb0, 2), zc1 = __shfl_xor(zb1, 2), zc2 = __shfl_xor(zb2, 2), zc3 = __shfl_xor(zb3, 2);
    float zd0 = hi ? zb0 : zc2, zd1 = hi ? zb1 : zc3, zd2 = hi ? zc0 : zb2, zd3 = hi ? zc1 : zb3;

    float ax = ((float)(ai % w + sd) + 0.5f) * s;
    float ay = ((float)(ai / w) + 0.5f) * s;
    ((float4*)pd_boxes)[tid] = make_float4(ax - ma0 * s, ay - ma1 * s, ax + ma2 * s, ay + ma3 * s);
    ((float4*)logZ)[tid] = make_float4(zd0, zd1, zd2, zd3);
    mask[tid] = 0u;
    packed[tid] = 0ull;

    // base BCE (target=0 term) for class channels 64+sd (+68+sd for sd<2)
    float bce = 0.f;
    {
        float4 x = *(const float4*)(base + (size_t)(64 + sd) * hw);
        bce += fmaxf(x.x, 0.f) + __logf(1.f + __expf(-fabsf(x.x)));
        bce += fmaxf(x.y, 0.f) + __logf(1.f + __expf(-fabsf(x.y)));
        bce += fmaxf(x.z, 0.f) + __logf(1.f + __expf(-fabsf(x.z)));
        bce += fmaxf(x.w, 0.f) + __logf(1.f + __expf(-fabsf(x.w)));
        if (sd < 2) {
            float4 y = *(const float4*)(base + (size_t)(68 + sd) * hw);
            bce += fmaxf(y.x, 0.f) + __logf(1.f + __expf(-fabsf(y.x)));
            bce += fmaxf(y.y, 0.f) + __logf(1.f + __expf(-fabsf(y.y)));
            bce += fmaxf(y.z, 0.f) + __logf(1.f + __expf(-fabsf(y.z)));
            bce += fmaxf(y.w, 0.f) + __logf(1.f + __expf(-fabsf(y.w)));
        }
    }

    // block reduce bce
    __shared__ float part[4];
    int lane = threadIdx.x & 63, wv = threadIdx.x >> 6;
    #pragma unroll
    for (int off = 32; off > 0; off >>= 1) bce += __shfl_down(bce, off);
    if (lane == 0) part[wv] = bce;
    __syncthreads();
    if (threadIdx.x == 0)
        partial_prep[blockIdx.x] = part[0] + part[1] + part[2] + part[3];
}

// prefer higher value; on tie prefer LOWER index (matches jax.lax.top_k)
__device__ __forceinline__ bool cand_better(float av, int ai_, float bv, int bi_) {
    if (av > bv) return true;
    if (av < bv) return false;
    if (ai_ < 0) return false;
    if (bi_ < 0) return true;
    return ai_ < bi_;
}

// ------- Kernel 2: per-(b,g) bounded cell scan + top-10 -> mask bits, row max,
//         per-anchor (align, g) argmax via packed 64-bit atomicMax -------
__global__ __launch_bounds__(256) void k_align(
        const float* __restrict__ targets,
        const float* __restrict__ pd_boxes,
        const float* __restrict__ p0, const float* __restrict__ p1, const float* __restrict__ p2,
        float* __restrict__ amax, unsigned int* __restrict__ mask,
        unsigned long long* __restrict__ packed) {
    __shared__ float cval[MAXCAND];
    __shared__ int   cidx[MAXCAND];
    __shared__ int   cnt_s;
    __shared__ float wtv[4][TOPK];
    __shared__ int   wti[4][TOPK];
    __shared__ float redf[4];

    int bg = blockIdx.x;
    int b = bg / G;
    int g = bg % G;
    const float* t = targets + (size_t)bg * 6;
    int lab = (int)t[1];
    const float* cb[3];
    cb[0] = p0 + (size_t)b * 70 * 6400 + (size_t)(64 + lab) * 6400;
    cb[1] = p1 + (size_t)b * 70 * 1600 + (size_t)(64 + lab) * 1600;
    cb[2] = p2 + (size_t)b * 70 * 400  + (size_t)(64 + lab) * 400;
    const float4* pb = (const float4*)pd_boxes + (size_t)b * A_TOT;
    unsigned long long* pk_row = packed + (size_t)b * A_TOT;

    float cx = t[2] * 640.f, cy = t[3] * 640.f;
    float hwd = t[4] * 320.f, hh = t[5] * 320.f;
    float gx1 = cx - hwd, gy1 = cy - hh, gx2 = cx + hwd, gy2 = cy + hh;

    const float sv3[3] = {8.f, 16.f, 32.f};
    const int   wv3[3] = {80, 40, 20};
    const int   ov3[3] = {0, 6400, 8000};
    int x0[3], y0[3], nx[3], ncell[3];
    int ntot = 0;
    #pragma unroll
    for (int l = 0; l < 3; ++l) {
        float s = sv3[l]; int w = wv3[l];
        int xa = max(0, (int)floorf(gx1 / s - 0.5f));
        int xb = min(w - 1, (int)ceilf(gx2 / s - 0.5f));
        int ya = max(0, (int)floorf(gy1 / s - 0.5f));
        int yb = min(w - 1, (int)ceilf(gy2 / s - 0.5f));
        x0[l] = xa; y0[l] = ya;
        nx[l] = max(0, xb - xa + 1);
        int nyl = max(0, yb - ya + 1);
        ncell[l] = nx[l] * nyl;
        ntot += ncell[l];
    }

    if (threadIdx.x == 0) cnt_s = 0;
    __syncthreads();

    float lmax = -1.f;
    for (int i = threadIdx.x; i < ntot; i += 256) {
        int l = 0, loc = i;
        if (loc >= ncell[0]) { loc -= ncell[0]; l = 1; }
        if (l == 1 && loc >= ncell[1]) { loc -= ncell[1]; l = 2; }
        int iy = loc / nx[l], ix = loc % nx[l];
        ix += x0[l]; iy += y0[l];
        float s = sv3[l]; int w = wv3[l];
        float ax = ((float)ix + 0.5f) * s, ay = ((float)iy + 0.5f) * s;
        int a = ov3[l] + iy * w + ix;
        float logit = cb[l][iy * w + ix];
        float al = align_from(t, logit, pb[a], ax, ay);
        if (al > 0.f) {
            lmax = fmaxf(lmax, al);
            // publish (align, g) for per-anchor argmax over ALL g (ties -> lowest g)
            unsigned long long pkv =
                ((unsigned long long)__float_as_uint(al) << 32) | (0xFFFFFFFFu - (unsigned)g);
            atomicMax(&pk_row[a], pkv);
            int p = atomicAdd(&cnt_s, 1);
            if (p < MAXCAND) { cval[p] = al; cidx[p] = a; }
        }
    }
    int lane = threadIdx.x & 63, wv = threadIdx.x >> 6;
    #pragma unroll
    for (int off = 32; off > 0; off >>= 1) lmax = fmaxf(lmax, __shfl_xor(lmax, off));
    if (lane == 0) redf[wv] = lmax;
    __syncthreads();   // covers redf AND cval/cidx visibility
    if (threadIdx.x == 0)
        amax[bg] = fmaxf(fmaxf(fmaxf(redf[0], redf[1]), fmaxf(redf[2], redf[3])), 0.f);

    int cnt = min(cnt_s, MAXCAND);
    float mv[MAXCAND / 256];
    int   mi[MAXCAND / 256];
    #pragma unroll
    for (int r = 0; r < MAXCAND / 256; ++r) {
        int p = threadIdx.x + r * 256;
        mv[r] = (p < cnt) ? cval[p] : -1.f;
        mi[r] = (p < cnt) ? cidx[p] : -1;
    }

    // per-wave top-10: no barriers, butterfly gives every lane the winner
    for (int it = 0; it < TOPK; ++it) {
        float v = -1.f; int vi = -1;
        #pragma unroll
        for (int r = 0; r < MAXCAND / 256; ++r)
            if (cand_better(mv[r], mi[r], v, vi)) { v = mv[r]; vi = mi[r]; }
        #pragma unroll
        for (int off = 1; off < 64; off <<= 1) {
            float ov = __shfl_xor(v, off);
            int   oi = __shfl_xor(vi, off);
            if (cand_better(ov, oi, v, vi)) { v = ov; vi = oi; }
        }
        if (vi < 0) {
            if (lane == 0)
                for (int j = it; j < TOPK; ++j) { wtv[wv][j] = -1.f; wti[wv][j] = -1; }
            break;
        }
        if (lane == 0) { wtv[wv][it] = v; wti[wv][it] = vi; }
        #pragma unroll
        for (int r = 0; r < MAXCAND / 256; ++r)
            if (mi[r] == vi) { mv[r] = -1.f; mi[r] = -1; }
    }
    __syncthreads();

    // wave 0 merges the 40 survivors (global top-10 is a subset of per-part top-10s)
    if (wv == 0) {
        float v4 = -1.f; int i4 = -1;
        if (lane < 4 * TOPK) { v4 = wtv[lane / TOPK][lane % TOPK]; i4 = wti[lane / TOPK][lane % TOPK]; }
        unsigned int* mrow = mask + (size_t)b * A_TOT;
        for (int it = 0; it < TOPK; ++it) {
            float v = v4; int vi = i4;
            #pragma unroll
            for (int off = 1; off < 64; off <<= 1) {
                float ov = __shfl_xor(v, off);
                int   oi = __shfl_xor(vi, off);
                if (cand_better(ov, oi, v, vi)) { v = ov; vi = oi; }
            }
            if (vi < 0) break;
            if (lane == 0) atomicOr(&mrow[vi], 1u << g);
            if (i4 == vi) { v4 = -1.f; i4 = -1; }
        }
    }
}

// ------- Kernel 3: fg-only losses (1 anchor/thread), per-block partials -------
// Multi-positive anchors resolve (align, g) from the packed argmax in ONE load
// (was: serial 20-iteration loop with a scattered logit load per GT).
__global__ __launch_bounds__(256) void k_loss(
        const float* __restrict__ targets,
        const float* __restrict__ pd_boxes, const float* __restrict__ logZ,
        const float* __restrict__ amax, const unsigned int* __restrict__ mask,
        const unsigned long long* __restrict__ packed,
        const float* __restrict__ p0, const float* __restrict__ p1, const float* __restrict__ p2,
        float* __restrict__ partial) {
    int idx = blockIdx.x * 256 + threadIdx.x;
    float bce_s = 0.f, bbox_s = 0.f, dfl_s = 0.f, fg_s = 0.f;
    if (idx < NBA) {
        unsigned int m = mask[idx];
        if (m != 0u) {
            int b = idx / A_TOT, a = idx % A_TOT;
            int lvl, ai, w_, hw; float s;
            anchor_decode(a, lvl, ai, w_, hw, s);
            const float* p = (lvl == 0) ? p0 : ((lvl == 1) ? p1 : p2);
            const float* base = p + (size_t)b * 70 * hw + ai;
            float ax = ((ai % w_) + 0.5f) * s, ay = ((ai / w_) + 0.5f) * s;
            float4 box = ((const float4*)pd_boxes)[idx];
            int gidx; float al; bool have_al;
            if (__popc(m) > 1) {
                // argmax over all g of align -> exactly the reference's `full` reassignment
                unsigned long long pk = packed[idx];
                gidx = (int)(0xFFFFFFFFu - (unsigned)(pk & 0xFFFFFFFFull));
                al = __uint_as_float((unsigned)(pk >> 32));
                have_al = true;
            } else {
                gidx = __ffs(m) - 1;
                al = 0.f;
                have_al = false;
            }
            const float* t = targets + ((size_t)b * G + gidx) * 6;
            int lab = (int)t[1];
            float logit = base[(size_t)(64 + lab) * hw];
            if (!have_al) al = align_from(t, logit, box, ax, ay);
            float cx = t[2] * 640.f, cy = t[3] * 640.f;
            float hwd = t[4] * 320.f, hh = t[5] * 320.f;
            float tbx1 = cx - hwd, tby1 = cy - hh, tbx2 = cx + hwd, tby2 = cy + hh;
            const float eps = 1e-7f;
            float x1 = fmaxf(box.x, tbx1), y1 = fmaxf(box.y, tby1);
            float x2 = fminf(box.z, tbx2), y2 = fminf(box.w, tby2);
            float inter = fmaxf(x2 - x1, 0.f) * fmaxf(y2 - y1, 0.f);
            float w1 = fmaxf(box.z - box.x, eps), h1 = fmaxf(box.w - box.y, eps);
            float w2 = fmaxf(tbx2 - tbx1, eps), h2 = fmaxf(tby2 - tby1, eps);
            float uni = w1 * h1 + w2 * h2 - inter + eps;
            float iou = inter / uni;
            float iou_fg = fmaxf(iou, 0.f);
            float sval = (al / (amax[b * G + gidx] + 1e-9f)) * iou_fg;
            bce_s = -logit * sval;          // BCE correction for target!=0
            fg_s = 1.f;
            // CIoU
            float cw = fmaxf(box.z, tbx2) - fminf(box.x, tbx1);
            float ch = fmaxf(box.w, tby2) - fminf(box.y, tby1);
            float c2 = cw * cw + ch * ch + eps;
            float dx = box.x + box.z - tbx1 - tbx2;
            float dy = box.y + box.w - tby1 - tby2;
            float rho2 = (dx * dx + dy * dy) * 0.25f;
            float dv = atanf(w2 / h2) - atanf(w1 / h1);
            float v = 0.40528473f * dv * dv;            // 4/pi^2
            float alpha = v / (v - iou + (1.f + eps));
            float ciou = iou - (rho2 / c2 + v * alpha);
            bbox_s = 1.f - ciou;
            // DFL
            float4 lzv = ((const float4*)logZ)[idx];
            float lz[4] = {lzv.x, lzv.y, lzv.z, lzv.w};
            float lt[4] = {(ax - tbx1) / s, (ay - tby1) / s, (tbx2 - ax) / s, (tby2 - ay) / s};
            #pragma unroll
            for (int sd = 0; sd < 4; ++sd) {
                float d = fminf(fmaxf(lt[sd], 0.f), (float)RM - 1.01f);
                int tl = (int)d;
                float wl = (float)(tl + 1) - d;
                float wr = d - (float)tl;
                float xl = base[(size_t)(sd * RM + tl) * hw];
                float xr = base[(size_t)(sd * RM + tl + 1) * hw];
                dfl_s += (lz[sd] - xl) * wl + (lz[sd] - xr) * wr;
            }
        }
    }
    __shared__ float part[4][4];
    int lane = threadIdx.x & 63, wv = threadIdx.x >> 6;
    #pragma unroll
    for (int off = 32; off > 0; off >>= 1) {
        bce_s  += __shfl_down(bce_s,  off);
        bbox_s += __shfl_down(bbox_s, off);
        dfl_s  += __shfl_down(dfl_s,  off);
        fg_s   += __shfl_down(fg_s,   off);
    }
    if (lane == 0) {
        part[wv][0] = bce_s; part[wv][1] = bbox_s;
        part[wv][2] = dfl_s; part[wv][3] = fg_s;
    }
    __syncthreads();
    if (threadIdx.x == 0) {
        float s0 = 0.f, s1 = 0.f, s2 = 0.f, s3 = 0.f;
        for (int i = 0; i < 4; ++i) {
            s0 += part[i][0]; s1 += part[i][1]; s2 += part[i][2]; s3 += part[i][3];
        }
        ((float4*)partial)[blockIdx.x] = make_float4(s0, s1, s2, s3);
    }
}

// ------- Kernel 4: reduce partials, combine -------
__global__ __launch_bounds__(256) void k_final(const float* __restrict__ partial,
                                               const float* __restrict__ partial_prep,
                                               float* __restrict__ out) {
    double s0 = 0., s1 = 0., s2 = 0., s3 = 0.;
    for (int i = threadIdx.x; i < NBLK_LOSS; i += 256) {
        float4 p = ((const float4*)partial)[i];
        s0 += p.x; s1 += p.y; s2 += p.z; s3 += p.w;
    }
    for (int i = threadIdx.x; i < NBLK_PREP; i += 256)
        s0 += partial_prep[i];
    #pragma unroll
    for (int off = 32; off > 0; off >>= 1) {
        s0 += __shfl_down(s0, off);
        s1 += __shfl_down(s1, off);
        s2 += __shfl_down(s2, off);
        s3 += __shfl_down(s3, off);
    }
    __shared__ double part[4][4];
    int lane = threadIdx.x & 63, wv = threadIdx.x >> 6;
    if (lane == 0) { part[wv][0] = s0; part[wv][1] = s1; part[wv][2] = s2; part[wv][3] = s3; }
    __syncthreads();
    if (threadIdx.x == 0) {
        double bce = 0., bbox = 0., dfl = 0., fgc = 0.;
        for (int i = 0; i < 4; ++i) {
            bce += part[i][0]; bbox += part[i][1]; dfl += part[i][2]; fgc += part[i][3];
        }
        double l_cls = bce / (double)A_TOT;
        double np_ = fmax(fgc, 1.0);
        double l_bbox = 7.5 * bbox / np_;
        double l_dfl = 1.5 * dfl / np_;
        out[0] = (float)(l_cls + l_bbox + l_dfl);
        out[1] = (float)l_cls;
        out[2] = (float)l_bbox;
        out[3] = 0.f;
        out[4] = (float)l_dfl;
    }
}

extern "C" void kernel_launch(void* const* d_in, const int* in_sizes, int n_in,
                              void* d_out, int out_size, void* d_ws, size_t ws_size,
                              hipStream_t stream) {
    const float* p0 = (const float*)d_in[0];
    const float* p1 = (const float*)d_in[1];
    const float* p2 = (const float*)d_in[2];
    const float* targets = (const float*)d_in[3];
    float* out = (float*)d_out;

    char* ws = (char*)d_ws;
    size_t off = 0;
    float* pd_boxes = (float*)(ws + off); off += (size_t)NBA * 4 * sizeof(float);
    float* logZ     = (float*)(ws + off); off += (size_t)NBA * 4 * sizeof(float);
    unsigned long long* packed = (unsigned long long*)(ws + off); off += (size_t)NBA * sizeof(unsigned long long);
    float* amax     = (float*)(ws + off); off += (size_t)BSZ * G * sizeof(float);
    unsigned int* mask = (unsigned int*)(ws + off); off += (size_t)NBA * sizeof(unsigned int);
    float* partial  = (float*)(ws + off); off += (size_t)NBLK_LOSS * 4 * sizeof(float);
    float* partial_prep = (float*)(ws + off); off += (size_t)NBLK_PREP * sizeof(float);

    k_prep<<<NBLK_PREP, 256, 0, stream>>>(p0, p1, p2, pd_boxes, logZ, mask, packed, partial_prep);
    k_align<<<BSZ * G, 256, 0, stream>>>(targets, pd_boxes, p0, p1, p2, amax, mask, packed);
    k_loss<<<NBLK_LOSS, 256, 0, stream>>>(targets, pd_boxes, logZ, amax, mask, packed,
                                          p0, p1, p2, partial);
    k_final<<<1, 256, 0, stream>>>(partial, partial_prep, out);
}